// Round 1
// baseline (926.088 us; speedup 1.0000x reference)
//
#include <hip/hip_runtime.h>
#include <hip/hip_bf16.h>
#include <hip/hip_fp16.h>

typedef __bf16 bf16x8 __attribute__((ext_vector_type(8)));
typedef float  f32x4  __attribute__((ext_vector_type(4)));

#define C_H 56
#define C_W 56
#define C_C 256
#define C_F 256
#define C_B 64
#define N_PIX (C_B * C_H * C_W)          // 200704
#define WB_ELEMS (9 * C_C * C_F)         // 589824
#define WB_BYTES (WB_ELEMS * 2)          // 1179648
#define ZBUF_BYTES 1024
#define XB_OFF (WB_BYTES + ZBUF_BYTES)   // 1180672 (16B aligned)
#define X_ELEMS (N_PIX * C_C)            // 51380224

// ---- prep: binarize + transpose weights: w[s][c][f] fp32 -> wbT[s][f][c] bf16 ----
__global__ void prep_w_kernel(const float* __restrict__ w, __bf16* __restrict__ wbT) {
    int idx = blockIdx.x * 256 + threadIdx.x;       // 589824 total
    int f = idx & 255;
    int c = (idx >> 8) & 255;
    int s = idx >> 16;
    float wf = w[idx];
    // fp16 round-trip, then sign (clip to [-1,1] does not change sign)
    float v = __half2float(__float2half(wf));
    float sgn = (v > 0.f) ? 1.f : ((v < 0.f) ? -1.f : 0.f);
    wbT[(s << 16) + (f << 8) + c] = (__bf16)sgn;
}

// ---- prep: zero page for out-of-bounds taps ----
__global__ void zero_kernel(float* __restrict__ z) {
    z[threadIdx.x] = 0.f;   // 256 floats = 1KB
}

// ---- prep: x fp32 -> bf16 ----
__global__ void prep_x_kernel(const float* __restrict__ x, __bf16* __restrict__ xb) {
    int i = blockIdx.x * 256 + threadIdx.x;         // one 8-elem chunk each; exact cover
    const f32x4* p = reinterpret_cast<const f32x4*>(x) + (size_t)i * 2;
    f32x4 a = p[0], b = p[1];
    bf16x8 o;
    o[0] = (__bf16)a[0]; o[1] = (__bf16)a[1]; o[2] = (__bf16)a[2]; o[3] = (__bf16)a[3];
    o[4] = (__bf16)b[0]; o[5] = (__bf16)b[1]; o[6] = (__bf16)b[2]; o[7] = (__bf16)b[3];
    reinterpret_cast<bf16x8*>(xb)[i] = o;
}

// ---- main conv: implicit GEMM, block = 64 pixels x 256 F, 4 waves (64px x 64f each) ----
template <bool PREX>
__global__ __launch_bounds__(256) void conv_kernel(
    const float* __restrict__ xf, const __bf16* __restrict__ xb,
    const __bf16* __restrict__ wbT, const char* __restrict__ zbuf,
    float* __restrict__ out) {

    const int lane = threadIdx.x & 63;
    const int wave = threadIdx.x >> 6;
    const int l15  = lane & 15;
    const int g    = lane >> 4;     // 0..3
    const int goff = g * 8;         // k-offset within 32-chunk (same map for A and B)
    const long m0  = (long)blockIdx.x * 64;
    const int fbase = wave * 64;

    int ry[4], rx[4];
    long rbase[4];
#pragma unroll
    for (int ai = 0; ai < 4; ++ai) {
        int rr = (int)m0 + ai * 16 + l15;
        int b = rr / 3136;
        int rem = rr - b * 3136;
        int yy = rem / 56;
        ry[ai] = yy;
        rx[ai] = rem - yy * 56;
        rbase[ai] = (long)rr * C_C;
    }

    f32x4 acc[4][4];
#pragma unroll
    for (int i = 0; i < 4; ++i)
#pragma unroll
        for (int j = 0; j < 4; ++j)
            acc[i][j] = (f32x4){0.f, 0.f, 0.f, 0.f};

    for (int s = 0; s < 9; ++s) {
        const int dy = s / 3 - 1;
        const int dx = (s - (s / 3) * 3) - 1;

        const __bf16* ab[4];
        const float*  af[4];
#pragma unroll
        for (int ai = 0; ai < 4; ++ai) {
            bool v = ((unsigned)(ry[ai] + dy) < 56u) & ((unsigned)(rx[ai] + dx) < 56u);
            long off = rbase[ai] + (long)(dy * C_W + dx) * C_C + goff;
            if (PREX) ab[ai] = v ? (xb + off) : ((const __bf16*)zbuf + goff);
            else      af[ai] = v ? (xf + off) : ((const float*)zbuf + goff);
        }
        const __bf16* bp = wbT + ((size_t)(s * 256 + fbase + l15)) * C_C + goff;

#pragma unroll
        for (int cc = 0; cc < 8; ++cc) {
            const int c0 = cc * 32;
            bf16x8 A[4], Bf[4];
#pragma unroll
            for (int ai = 0; ai < 4; ++ai) {
                if (PREX) {
                    A[ai] = *reinterpret_cast<const bf16x8*>(ab[ai] + c0);
                } else {
                    const f32x4* p = reinterpret_cast<const f32x4*>(af[ai] + c0);
                    f32x4 u = p[0], w2 = p[1];
                    bf16x8 t;
                    t[0] = (__bf16)u[0]; t[1] = (__bf16)u[1]; t[2] = (__bf16)u[2]; t[3] = (__bf16)u[3];
                    t[4] = (__bf16)w2[0]; t[5] = (__bf16)w2[1]; t[6] = (__bf16)w2[2]; t[7] = (__bf16)w2[3];
                    A[ai] = t;
                }
            }
#pragma unroll
            for (int bj = 0; bj < 4; ++bj)
                Bf[bj] = *reinterpret_cast<const bf16x8*>(bp + bj * 16 * C_C + c0);
#pragma unroll
            for (int ai = 0; ai < 4; ++ai)
#pragma unroll
                for (int bj = 0; bj < 4; ++bj)
                    acc[ai][bj] = __builtin_amdgcn_mfma_f32_16x16x32_bf16(A[ai], Bf[bj], acc[ai][bj], 0, 0, 0);
        }
    }

    // epilogue: D layout col=lane&15, row=(lane>>4)*4+j  [m89-verified]
#pragma unroll
    for (int ai = 0; ai < 4; ++ai) {
#pragma unroll
        for (int j = 0; j < 4; ++j) {
            long row = m0 + ai * 16 + g * 4 + j;
            float* op = out + row * C_F + fbase + l15;
#pragma unroll
            for (int bj = 0; bj < 4; ++bj)
                op[bj * 16] = acc[ai][bj][j];
        }
    }
}

extern "C" void kernel_launch(void* const* d_in, const int* in_sizes, int n_in,
                              void* d_out, int out_size, void* d_ws, size_t ws_size,
                              hipStream_t stream) {
    const float* x = (const float*)d_in[0];
    const float* w = (const float*)d_in[1];
    float* out = (float*)d_out;

    char* ws = (char*)d_ws;
    __bf16* wbT = (__bf16*)ws;
    char* zbuf = ws + WB_BYTES;
    __bf16* xb = (__bf16*)(ws + XB_OFF);

    const bool prex = ws_size >= (size_t)XB_OFF + (size_t)X_ELEMS * 2;

    prep_w_kernel<<<WB_ELEMS / 256, 256, 0, stream>>>(w, wbT);
    zero_kernel<<<1, 256, 0, stream>>>((float*)zbuf);

    if (prex) {
        prep_x_kernel<<<X_ELEMS / 8 / 256, 256, 0, stream>>>(x, xb);
        conv_kernel<true><<<N_PIX / 64, 256, 0, stream>>>(nullptr, xb, wbT, zbuf, out);
    } else {
        conv_kernel<false><<<N_PIX / 64, 256, 0, stream>>>(x, nullptr, wbT, zbuf, out);
    }
}

// Round 2
// 305.095 us; speedup vs baseline: 3.0354x; 3.0354x over previous
//
#include <hip/hip_runtime.h>
#include <hip/hip_bf16.h>
#include <hip/hip_fp16.h>

typedef __bf16 bf16x8 __attribute__((ext_vector_type(8)));
typedef float  f32x4  __attribute__((ext_vector_type(4)));

#define C_H 56
#define C_W 56
#define C_C 256
#define C_F 256
#define C_B 64
#define N_PIX (C_B * C_H * C_W)          // 200704
#define WB_ELEMS (9 * C_C * C_F)         // 589824
#define WB_BYTES (WB_ELEMS * 2)          // 1179648
#define ZBUF_BYTES 1024
#define XB_OFF (WB_BYTES + ZBUF_BYTES)   // 1180672 (16B aligned)
#define X_ELEMS (N_PIX * C_C)            // 51380224

#define GLOAD_LDS16(g, l)                                                   \
    __builtin_amdgcn_global_load_lds(                                        \
        (const __attribute__((address_space(1))) void*)(g),                  \
        (__attribute__((address_space(3))) void*)(l), 16, 0, 0)

// ---- prep: binarize + transpose weights: w[s][c][f] fp32 -> wbT[s][f][c] bf16 ----
__global__ void prep_w_kernel(const float* __restrict__ w, __bf16* __restrict__ wbT) {
    int idx = blockIdx.x * 256 + threadIdx.x;       // 589824 total
    int f = idx & 255;
    int c = (idx >> 8) & 255;
    int s = idx >> 16;
    float wf = w[idx];
    float v = __half2float(__float2half(wf));       // fp16 round-trip
    float sgn = (v > 0.f) ? 1.f : ((v < 0.f) ? -1.f : 0.f);
    wbT[(s << 16) + (f << 8) + c] = (__bf16)sgn;
}

__global__ void zero_kernel(float* __restrict__ z) {
    z[threadIdx.x] = 0.f;   // 1KB zero page
}

__global__ void prep_x_kernel(const float* __restrict__ x, __bf16* __restrict__ xb) {
    int i = blockIdx.x * 256 + threadIdx.x;
    const f32x4* p = reinterpret_cast<const f32x4*>(x) + (size_t)i * 2;
    f32x4 a = p[0], b = p[1];
    bf16x8 o;
    o[0] = (__bf16)a[0]; o[1] = (__bf16)a[1]; o[2] = (__bf16)a[2]; o[3] = (__bf16)a[3];
    o[4] = (__bf16)b[0]; o[5] = (__bf16)b[1]; o[6] = (__bf16)b[2]; o[7] = (__bf16)b[3];
    reinterpret_cast<bf16x8*>(xb)[i] = o;
}

// ---- main conv: m97-structure implicit GEMM ----
// tile 128px x 128F, 4 waves (2x2, each 64x64), BK=64, s-major K (36 steps)
// LDS: A[128][64] bf16 + B[128][64] bf16 = 32KB, single buffer, XOR-swizzled
__global__ __launch_bounds__(256, 4) void conv_mfma_kernel(
    const char* __restrict__ xbp,      // bf16 x, as bytes
    const char* __restrict__ wbp,      // bf16 wbT[s][f][c], as bytes
    const char* __restrict__ zp,       // >=128B zeros
    float* __restrict__ out) {

    __shared__ __align__(16) char smA[128 * 128];   // 128 rows x 128B (BK=64 bf16)
    __shared__ __align__(16) char smB[128 * 128];

    // ---- XCD-aware bijective swizzle: 3136 blocks, 392 per XCD ----
    const int nbid = (blockIdx.x & 7) * 392 + (blockIdx.x >> 3);
    const int mtile = nbid >> 1;            // 0..1567
    const int ftile = nbid & 1;             // 0..1  (A-sharing pair adjacent)
    const long m0 = (long)mtile * 128;
    const int fbase0 = ftile * 128;

    const int tid  = threadIdx.x;
    const int lane = tid & 63;
    const int wave = tid >> 6;
    const int l15  = lane & 15;
    const int g4   = lane >> 4;             // 0..3
    const int wm   = wave >> 1;             // 0..1
    const int wn   = wave & 1;              // 0..1
    const int sa   = (l15 & 7) << 4;        // read-side swizzle term

    // ---- staging geometry: thread covers 4 chunks of 16B in each of A,B ----
    const int trow  = tid >> 3;             // 0..31
    const int cbyte = (tid & 7) * 16;       // 0..112

    int rr[4], yy[4], xx[4], swzc[4];
#pragma unroll
    for (int r = 0; r < 4; ++r) {
        int rowl = r * 32 + trow;           // 0..127
        int p = (int)m0 + rowl;
        rr[r] = p;
        int rem = p % 3136;
        yy[r] = rem / 56;
        xx[r] = rem - yy[r] * 56;
        swzc[r] = cbyte ^ ((rowl & 7) << 4);   // inverse-swizzled source col
    }

    f32x4 acc[4][4];
#pragma unroll
    for (int i = 0; i < 4; ++i)
#pragma unroll
        for (int j = 0; j < 4; ++j)
            acc[i][j] = (f32x4){0.f, 0.f, 0.f, 0.f};

    for (int s = 0; s < 9; ++s) {
        const int dy = s / 3 - 1;
        const int dx = (s - (s / 3) * 3) - 1;
        const int doff = dy * 56 + dx;

        // per-s A row validity + base byte offsets
        const char* abase[4];
#pragma unroll
        for (int r = 0; r < 4; ++r) {
            bool v = ((unsigned)(yy[r] + dy) < 56u) & ((unsigned)(xx[r] + dx) < 56u);
            abase[r] = v ? (xbp + ((size_t)(rr[r] + doff) * 512 + swzc[r]))
                         : (zp + swzc[r]);
        }
        const char* bbase = wbp + ((size_t)((s << 8) + fbase0) * 512);

        for (int cc = 0; cc < 4; ++cc) {
            const size_t c0b = (size_t)cc * 128;

            // ---- stage A (16KB) + B (16KB), linear LDS dest, pre-swizzled source ----
#pragma unroll
            for (int r = 0; r < 4; ++r) {
                const char* ga = abase[r] + c0b;
                GLOAD_LDS16(ga, smA + r * 4096 + tid * 16);
            }
#pragma unroll
            for (int r = 0; r < 4; ++r) {
                int fl = r * 32 + trow;
                const char* gb = bbase + (size_t)fl * 512 + c0b + swzc[r];
                GLOAD_LDS16(gb, smB + r * 4096 + tid * 16);
            }
            __syncthreads();   // vmcnt(0) drain: staging complete

            // ---- compute: 16 ds_read_b128 + 32 MFMA ----
#pragma unroll
            for (int kk = 0; kk < 2; ++kk) {
                const int colx = (kk * 64 + g4 * 16) ^ sa;   // swizzled read col
                bf16x8 A[4], Bf[4];
#pragma unroll
                for (int ai = 0; ai < 4; ++ai) {
                    int row = wm * 64 + ai * 16 + l15;
                    A[ai] = *reinterpret_cast<const bf16x8*>(smA + row * 128 + colx);
                }
#pragma unroll
                for (int bj = 0; bj < 4; ++bj) {
                    int row = wn * 64 + bj * 16 + l15;
                    Bf[bj] = *reinterpret_cast<const bf16x8*>(smB + row * 128 + colx);
                }
#pragma unroll
                for (int ai = 0; ai < 4; ++ai)
#pragma unroll
                    for (int bj = 0; bj < 4; ++bj)
                        acc[ai][bj] = __builtin_amdgcn_mfma_f32_16x16x32_bf16(
                            A[ai], Bf[bj], acc[ai][bj], 0, 0, 0);
            }
            __syncthreads();   // before next stage overwrites
        }
    }

    // ---- epilogue: D col=lane&15, row=(lane>>4)*4+j ----
#pragma unroll
    for (int ai = 0; ai < 4; ++ai) {
#pragma unroll
        for (int j = 0; j < 4; ++j) {
            long row = m0 + wm * 64 + ai * 16 + g4 * 4 + j;
            float* op = out + row * C_F + fbase0 + wn * 64 + l15;
#pragma unroll
            for (int bj = 0; bj < 4; ++bj)
                op[bj * 16] = acc[ai][bj][j];
        }
    }
}

// ---- fallback (small ws): direct-from-global version (R1 kernel) ----
__global__ __launch_bounds__(256) void conv_fallback_kernel(
    const float* __restrict__ xf,
    const __bf16* __restrict__ wbT, const char* __restrict__ zbuf,
    float* __restrict__ out) {

    const int lane = threadIdx.x & 63;
    const int wave = threadIdx.x >> 6;
    const int l15  = lane & 15;
    const int g    = lane >> 4;
    const int goff = g * 8;
    const long m0  = (long)blockIdx.x * 64;
    const int fbase = wave * 64;

    int ry[4], rx[4];
    long rbase[4];
#pragma unroll
    for (int ai = 0; ai < 4; ++ai) {
        int rr = (int)m0 + ai * 16 + l15;
        int b = rr / 3136;
        int rem = rr - b * 3136;
        int yy2 = rem / 56;
        ry[ai] = yy2;
        rx[ai] = rem - yy2 * 56;
        rbase[ai] = (long)rr * C_C;
    }

    f32x4 acc[4][4];
#pragma unroll
    for (int i = 0; i < 4; ++i)
#pragma unroll
        for (int j = 0; j < 4; ++j)
            acc[i][j] = (f32x4){0.f, 0.f, 0.f, 0.f};

    for (int s = 0; s < 9; ++s) {
        const int dy = s / 3 - 1;
        const int dx = (s - (s / 3) * 3) - 1;
        const float* af[4];
#pragma unroll
        for (int ai = 0; ai < 4; ++ai) {
            bool v = ((unsigned)(ry[ai] + dy) < 56u) & ((unsigned)(rx[ai] + dx) < 56u);
            long off = rbase[ai] + (long)(dy * C_W + dx) * C_C + goff;
            af[ai] = v ? (xf + off) : ((const float*)zbuf + goff);
        }
        const __bf16* bp = wbT + ((size_t)(s * 256 + fbase + l15)) * C_C + goff;

#pragma unroll
        for (int cc = 0; cc < 8; ++cc) {
            const int c0 = cc * 32;
            bf16x8 A[4], Bf[4];
#pragma unroll
            for (int ai = 0; ai < 4; ++ai) {
                const f32x4* p = reinterpret_cast<const f32x4*>(af[ai] + c0);
                f32x4 u = p[0], w2 = p[1];
                bf16x8 t;
                t[0] = (__bf16)u[0]; t[1] = (__bf16)u[1]; t[2] = (__bf16)u[2]; t[3] = (__bf16)u[3];
                t[4] = (__bf16)w2[0]; t[5] = (__bf16)w2[1]; t[6] = (__bf16)w2[2]; t[7] = (__bf16)w2[3];
                A[ai] = t;
            }
#pragma unroll
            for (int bj = 0; bj < 4; ++bj)
                Bf[bj] = *reinterpret_cast<const bf16x8*>(bp + bj * 16 * C_C + c0);
#pragma unroll
            for (int ai = 0; ai < 4; ++ai)
#pragma unroll
                for (int bj = 0; bj < 4; ++bj)
                    acc[ai][bj] = __builtin_amdgcn_mfma_f32_16x16x32_bf16(A[ai], Bf[bj], acc[ai][bj], 0, 0, 0);
        }
    }

#pragma unroll
    for (int ai = 0; ai < 4; ++ai) {
#pragma unroll
        for (int j = 0; j < 4; ++j) {
            long row = m0 + ai * 16 + g * 4 + j;
            float* op = out + row * C_F + fbase + l15;
#pragma unroll
            for (int bj = 0; bj < 4; ++bj)
                op[bj * 16] = acc[ai][bj][j];
        }
    }
}

extern "C" void kernel_launch(void* const* d_in, const int* in_sizes, int n_in,
                              void* d_out, int out_size, void* d_ws, size_t ws_size,
                              hipStream_t stream) {
    const float* x = (const float*)d_in[0];
    const float* w = (const float*)d_in[1];
    float* out = (float*)d_out;

    char* ws = (char*)d_ws;
    __bf16* wbT = (__bf16*)ws;
    char* zbuf = ws + WB_BYTES;
    __bf16* xb = (__bf16*)(ws + XB_OFF);

    const bool prex = ws_size >= (size_t)XB_OFF + (size_t)X_ELEMS * 2;

    prep_w_kernel<<<WB_ELEMS / 256, 256, 0, stream>>>(w, wbT);
    zero_kernel<<<1, 256, 0, stream>>>((float*)zbuf);

    if (prex) {
        prep_x_kernel<<<X_ELEMS / 8 / 256, 256, 0, stream>>>(x, xb);
        conv_mfma_kernel<<<N_PIX / 128 * 2, 256, 0, stream>>>(
            (const char*)xb, (const char*)wbT, zbuf, out);
    } else {
        conv_fallback_kernel<<<N_PIX / 64, 256, 0, stream>>>(x, wbT, zbuf, out);
    }
}